// Round 15
// baseline (407.522 us; speedup 1.0000x reference)
//
#include <hip/hip_runtime.h>
#include <hip/hip_bf16.h>
#include <stdint.h>

typedef __bf16 bf16;
typedef __bf16 bf16x8 __attribute__((ext_vector_type(8)));
typedef __bf16 bf16x4 __attribute__((ext_vector_type(4)));
typedef float f32x4v __attribute__((ext_vector_type(4)));

#define SEQ    2048
#define DMODEL 2048
#define DI     4096
#define NH     64
#define PDIM   64
#define CHUNKL 128
#define NCH    16
#define CONVD  4352
#define DPROJ  8512
#define ZLD    8704   // zxbcdt leading dim, padded to 34*256
#define NTOK   4096
#define LP     136    // padded LDS leading dim for middle kernels

__device__ __forceinline__ float sigmoid_f(float x){ return 1.f/(1.f+expf(-x)); }
__device__ __forceinline__ float silu_f(float x){ return x*sigmoid_f(x); }
__device__ __forceinline__ float softplus_f(float x){ return x > 20.f ? x : log1pf(expf(x)); }

// ---------------- fused conversions: hs->bf16 | W_in->bf16 padded | W_out->bf16 ----------------
__global__ __launch_bounds__(256) void cvt_all_kernel(const float* __restrict__ hs,
                                                      const float* __restrict__ W_in,
                                                      const float* __restrict__ W_out,
                                                      bf16* __restrict__ hsb,
                                                      bf16* __restrict__ winb,
                                                      bf16* __restrict__ woutb){
    int blk = blockIdx.x;
    if (blk < 8192){
        int i = (blk*256 + threadIdx.x)*4;
        float4 v = *(const float4*)&hs[i];
        bf16x4 o; o[0]=(bf16)v.x; o[1]=(bf16)v.y; o[2]=(bf16)v.z; o[3]=(bf16)v.w;
        *(bf16x4*)&hsb[i] = o;
    } else if (blk < 25600){
        int i = ((blk-8192)*256 + threadIdx.x)*4;   // over 8704*2048
        int r = i >> 11;
        bf16x4 o;
        if (r < DPROJ){
            float4 v = *(const float4*)&W_in[i];
            o[0]=(bf16)v.x; o[1]=(bf16)v.y; o[2]=(bf16)v.z; o[3]=(bf16)v.w;
        } else {
            o[0]=(bf16)0.f; o[1]=(bf16)0.f; o[2]=(bf16)0.f; o[3]=(bf16)0.f;
        }
        *(bf16x4*)&winb[i] = o;
    } else {
        int i = ((blk-25600)*256 + threadIdx.x)*4;
        float4 v = *(const float4*)&W_out[i];
        bf16x4 o; o[0]=(bf16)v.x; o[1]=(bf16)v.y; o[2]=(bf16)v.z; o[3]=(bf16)v.w;
        *(bf16x4*)&woutb[i] = o;
    }
}

// ============ GEMM1: 128x256 tile, BK=32, 48KB LDS, 2 blocks/CU ============
// Single-phase K-loop: {vmcnt(3) -> barrier -> 8 ds_reads -> lgkmcnt(0) -> 16 MFMA
// -> barrier -> stage(cur, t+2)}. FIFO proof: 3 loads/tile, prologue 6 outstanding;
// vmcnt(3)@t retires exactly tile t's 3. WAR: stage after barrier following reads.
// Covers full N=8704 (34 N-tiles) incl. dt cols -> f32 side-channel (no tail kernel).
__global__ __launch_bounds__(512, 4) void gemm1_kernel(const bf16* __restrict__ A,
                                                       const bf16* __restrict__ Bmat,
                                                       bf16* __restrict__ Cz,
                                                       float* __restrict__ dtf,
                                                       int NXB, int NYB, int K){
    __shared__ __align__(16) bf16 lds[2][12288];   // [buf][ A(128x32=4096) | B(256x32=8192) ]
    const int tid  = threadIdx.x;
    const int w    = tid >> 6;
    const int lane = tid & 63;
    const int wm   = w >> 2, wn = w & 3;           // 2M x 4N wave grid; per-wave 64x64

    int bid = blockIdx.x, nb = gridDim.x;
    int wg  = (bid & 7)*(nb >> 3) + (bid >> 3);    // XCD-bijective (nb%8==0)
    const int SW = 8;
    int sup = wg / (SW*NYB);
    int rr  = wg % (SW*NYB);
    int x0  = sup*SW;
    int wl  = (NXB - x0 < SW) ? (NXB - x0) : SW;
    int x   = x0 + rr % wl;
    int y   = rr / wl;
    const int tm = y*128, tn = x*256;
    const int KT = K >> 5;                         // BK=32

    f32x4v acc[4][4];
    #pragma unroll
    for (int i=0;i<4;i++)
        #pragma unroll
        for (int j=0;j<4;j++) acc[i][j] = {0.f,0.f,0.f,0.f};
    bf16x8 af[4], bfr[4];

    // ---- hoisted addressing ----
    // stage A (1 issue): lane covers row=tid>>2 of 128, slot_lin=tid&3 (16B slots)
    // stage B (2 issues): row = i*128 + (tid>>2)
    const bf16* srcA1;
    const bf16* srcB2[2];
    {
        int row = tid >> 2;
        int gslot = (tid & 3) ^ ((row >> 1) & 3);
        srcA1 = A + (long)(tm + row)*K + gslot*8;
        #pragma unroll
        for (int i=0;i<2;i++){
            int rb = i*128 + row;
            int gs = (tid & 3) ^ ((rb >> 1) & 3);
            srcB2[i] = Bmat + (long)(tn + rb)*K + gs*8;
        }
    }
    int aoff[4], boff[4];
    #pragma unroll
    for (int mi=0;mi<4;mi++){
        int ra = wm*64 + mi*16 + (lane&15);
        int slot = (lane>>4) ^ ((ra>>1)&3);
        aoff[mi] = ra*32 + slot*8;
    }
    #pragma unroll
    for (int ni=0;ni<4;ni++){
        int rb = wn*64 + ni*16 + (lane&15);
        int slot = (lane>>4) ^ ((rb>>1)&3);
        boff[ni] = 4096 + rb*32 + slot*8;
    }

    auto stage = [&](int buf, int t){
        long koff = (long)t*32;
        {
            bf16* dst = &lds[buf][0] + (size_t)w*512;       // A: one 8KB issue
            __builtin_amdgcn_global_load_lds(
                (const __attribute__((address_space(1))) void*)(srcA1 + koff),
                (__attribute__((address_space(3))) void*)dst, 16, 0, 0);
        }
        #pragma unroll
        for (int i=0;i<2;i++){
            bf16* dst = &lds[buf][4096] + (size_t)(i*4096 + w*512);
            __builtin_amdgcn_global_load_lds(
                (const __attribute__((address_space(1))) void*)(srcB2[i] + koff),
                (__attribute__((address_space(3))) void*)dst, 16, 0, 0);
        }
    };

    // ---- prologue: tiles 0,1 (3 loads each) ----
    stage(0, 0);
    if (KT > 1) stage(1, 1);

    int cur = 0;
    for (int t = 0; t < KT; ++t){
        const bf16* bufc = &lds[cur][0];
        // retire tile t's 3 loads (keep t+1's 3 in flight), then block barrier
        if (t+1 < KT){ asm volatile("s_waitcnt vmcnt(3)" ::: "memory"); }
        else         { asm volatile("s_waitcnt vmcnt(0)" ::: "memory"); }
        __builtin_amdgcn_sched_barrier(0);
        __builtin_amdgcn_s_barrier();
        __builtin_amdgcn_sched_barrier(0);
        // 8 fragment reads
        #pragma unroll
        for (int mi=0;mi<4;mi++) af[mi]  = *(const bf16x8*)&bufc[aoff[mi]];
        #pragma unroll
        for (int ni=0;ni<4;ni++) bfr[ni] = *(const bf16x8*)&bufc[boff[ni]];
        asm volatile("s_waitcnt lgkmcnt(0)" ::: "memory");
        __builtin_amdgcn_sched_barrier(0);
        // 16 MFMA
        __builtin_amdgcn_s_setprio(1);
        #pragma unroll
        for (int mi=0;mi<4;mi++)
            #pragma unroll
            for (int ni=0;ni<4;ni++)
                acc[mi][ni] = __builtin_amdgcn_mfma_f32_16x16x32_bf16(af[mi], bfr[ni], acc[mi][ni], 0,0,0);
        __builtin_amdgcn_s_setprio(0);
        __builtin_amdgcn_sched_barrier(0);
        // reads complete block-wide, then re-stage this buffer for t+2
        __builtin_amdgcn_s_barrier();
        __builtin_amdgcn_sched_barrier(0);
        if (t+2 < KT) stage(cur, t+2);
        cur ^= 1;
    }

    // ---- epilogue: bf16 C + f32 dt side-channel ----
    const int er = (lane>>4)*4, ec = lane&15;
    #pragma unroll
    for (int mi=0;mi<4;mi++)
        #pragma unroll
        for (int ni=0;ni<4;ni++){
            long r0 = tm + wm*64 + mi*16 + er;
            int  c0 = tn + wn*64 + ni*16 + ec;
            #pragma unroll
            for (int j=0;j<4;j++){
                float val = acc[mi][ni][j];
                Cz[(r0+j)*ZLD + c0] = (bf16)val;
                if (c0 >= 8448 && c0 < 8512)
                    dtf[(r0+j)*64 + (c0 - 8448)] = val;
            }
        }
}

// ============ shared GEMM fragment macros (GEMM2) ============
#define READ_AF(BUFP, QM, AF)                                                          \
    {                                                                                  \
        _Pragma("unroll")                                                              \
        for (int i=0;i<4;i++)                                                          \
            _Pragma("unroll")                                                          \
            for (int k2=0;k2<2;k2++)                                                   \
                AF[i][k2] = *(const bf16x8*)&(BUFP)[aoff[i][k2] + (QM)*8192];          \
    }

#define READ_B(BUFP, QN, BFR)                                                          \
    {                                                                                  \
        _Pragma("unroll")                                                              \
        for (int nf=0;nf<2;nf++)                                                       \
            _Pragma("unroll")                                                          \
            for (int k2=0;k2<2;k2++)                                                   \
                BFR[nf][k2] = *(const bf16x8*)&(BUFP)[boff[nf][k2] + (QN)*8192];       \
    }

#define MMA_QA(AF, QM, QN, BFR)                                                        \
    {                                                                                  \
        __builtin_amdgcn_s_setprio(1);                                                 \
        _Pragma("unroll")                                                              \
        for (int i=0;i<4;i++)                                                          \
            _Pragma("unroll")                                                          \
            for (int nf=0;nf<2;nf++)                                                   \
                _Pragma("unroll")                                                      \
                for (int k2=0;k2<2;k2++)                                               \
                    acc[(QM)*4+i][(QN)*2+nf] = __builtin_amdgcn_mfma_f32_16x16x32_bf16( \
                        AF[i][k2], BFR[nf][k2], acc[(QM)*4+i][(QN)*2+nf], 0,0,0);      \
        __builtin_amdgcn_s_setprio(0);                                                 \
    }

#define SBAR() do { __builtin_amdgcn_sched_barrier(0);                                 \
                    __builtin_amdgcn_s_barrier();                                      \
                    asm volatile("s_waitcnt lgkmcnt(0)" ::: "memory");                 \
                    __builtin_amdgcn_sched_barrier(0); } while(0)

// ============ 256x128 triple-buffered bf16 GEMM (GEMM2): merged-read ============
__global__ __launch_bounds__(512) void gemm256x128_kernel(const bf16* __restrict__ A,
                                                          const bf16* __restrict__ Bmat,
                                                          float* __restrict__ C,
                                                          int NXB, int NYB, int K, int ldc){
    __shared__ __align__(16) bf16 lds[3][24576];   // [buf][A(16384) | B(8192)]
    const int tid  = threadIdx.x;
    const int w    = tid >> 6;
    const int lane = tid & 63;
    const int wm   = w >> 2, wn = w & 3;

    int bid = blockIdx.x, nb = gridDim.x;
    int wg = (bid & 7)*(nb >> 3) + (bid >> 3);
    const int SW = 8;
    int sup = wg / (SW*NYB);
    int rr  = wg % (SW*NYB);
    int x0  = sup*SW;
    int wl  = (NXB - x0 < SW) ? (NXB - x0) : SW;
    int x   = x0 + rr % wl;
    int y   = rr / wl;
    const int tm = y*256, tn = x*128;
    const int KT = K >> 6;

    f32x4v acc[8][2];
    #pragma unroll
    for (int i=0;i<8;i++)
        #pragma unroll
        for (int j=0;j<2;j++) acc[i][j] = {0.f,0.f,0.f,0.f};
    bf16x8 af[4][2], af1[4][2];
    bf16x8 bfr[2][2];

    const bf16* srcA[2][2];
    const bf16* srcB[2];
    #pragma unroll
    for (int r0h=0;r0h<2;r0h++)
        #pragma unroll
        for (int i=0;i<2;i++){
            int lr = r0h*128 + i*64 + (tid>>3);
            int growA = tm + ((lr>>6)&1)*128 + (lr>>7)*64 + (lr&63);
            int gslot = (tid&7) ^ (lr&7);
            srcA[r0h][i] = A + (long)growA*K + gslot*8;
        }
    #pragma unroll
    for (int i=0;i<2;i++){
        int lr = i*64 + (tid>>3);
        int gslot = (tid&7) ^ (lr&7);
        srcB[i] = Bmat + (long)(tn + lr)*K + gslot*8;
    }
    int aoff[4][2], boff[2][2];
    #pragma unroll
    for (int i=0;i<4;i++)
        #pragma unroll
        for (int k2=0;k2<2;k2++){
            int ra0 = wm*64 + i*16 + (lane&15);
            int slot = (k2*4 + (lane>>4)) ^ (ra0&7);
            aoff[i][k2] = ra0*64 + slot*8;
        }
    #pragma unroll
    for (int nf=0;nf<2;nf++)
        #pragma unroll
        for (int k2=0;k2<2;k2++){
            int rb0 = wn*32 + nf*16 + (lane&15);
            int slot = (k2*4 + (lane>>4)) ^ (rb0&7);
            boff[nf][k2] = 16384 + rb0*64 + slot*8;
        }

    auto stageA = [&](int buf, int t, int r0h){
        long koff = (long)t*64;
        #pragma unroll
        for (int i=0;i<2;i++){
            bf16* dst = &lds[buf][0] + (size_t)(r0h*128 + i*64 + w*8)*64;
            __builtin_amdgcn_global_load_lds(
                (const __attribute__((address_space(1))) void*)(srcA[r0h][i] + koff),
                (__attribute__((address_space(3))) void*)dst, 16, 0, 0);
        }
    };
    auto stageB = [&](int buf, int t){
        long koff = (long)t*64;
        #pragma unroll
        for (int i=0;i<2;i++){
            bf16* dst = &lds[buf][16384] + (size_t)(i*64 + w*8)*64;
            __builtin_amdgcn_global_load_lds(
                (const __attribute__((address_space(1))) void*)(srcB[i] + koff),
                (__attribute__((address_space(3))) void*)dst, 16, 0, 0);
        }
    };

    stageA(0, 0, 0); stageA(0, 0, 1); stageB(0, 0);
    if (KT > 1){ stageA(1, 1, 0); stageA(1, 1, 1); stageB(1, 1); }
    asm volatile("s_waitcnt vmcnt(6)" ::: "memory");   // tile-0 A+B complete
    __builtin_amdgcn_s_barrier();

    int cur = 0;
    for (int t = 0; t < KT; ++t){
        int stb = cur + 2; if (stb >= 3) stb -= 3;
        const bf16* bufc = &lds[cur][0];
        READ_AF(bufc, 0, af)
        READ_AF(bufc, 1, af1)
        READ_B(bufc, 0, bfr)
        if (t+2 < KT){ stageA(stb, t+2, 0); stageA(stb, t+2, 1); }
        SBAR();
        MMA_QA(af, 0, 0, bfr)
        if (t+2 < KT){
            stageB(stb, t+2);
            asm volatile("s_waitcnt vmcnt(6)" ::: "memory");
        } else {
            asm volatile("s_waitcnt vmcnt(0)" ::: "memory");
        }
        SBAR();
        MMA_QA(af1, 1, 0, bfr)
        cur = (cur == 2) ? 0 : cur + 1;
    }

    const int er = (lane>>4)*4, ec = lane&15;
    #pragma unroll
    for (int mi=0;mi<8;mi++)
        #pragma unroll
        for (int ni=0;ni<2;ni++){
            long r0 = tm + wm*128 + mi*16 + er;
            int  c0 = tn + wn*32 + ni*16 + ec;
            #pragma unroll
            for (int j=0;j<4;j++)
                C[(r0+j)*ldc + c0] = acc[mi][ni][j];
        }
}

// ---------------- merged: conv (blocks 0..2559) + dtcum (blocks 2560..3071) ----------------
__global__ __launch_bounds__(256) void mid1_kernel(const bf16* __restrict__ zx,
                                                   const float* __restrict__ Wc,
                                                   const float* __restrict__ bc,
                                                   const float* __restrict__ dtf,
                                                   const float* __restrict__ A_log,
                                                   const float* __restrict__ dt_bias,
                                                   bf16* __restrict__ xc,
                                                   float* __restrict__ dtv,
                                                   float* __restrict__ dacs,
                                                   float* __restrict__ cdec){
    int blk = blockIdx.x;
    if (blk < 2560){
        int by = blk/5, bx = blk%5;
        int c4 = bx*256 + threadIdx.x;
        if (c4 >= 1088) return;
        int ch = c4*4;
        int b = by >> 8, t0 = (by & 255)*8;
        float4 tap[4];
        #pragma unroll
        for (int e=0;e<4;e++) tap[e] = *(const float4*)&Wc[(ch+e)*4];
        float4 bq = *(const float4*)&bc[ch];
        float bca[4] = {bq.x, bq.y, bq.z, bq.w};
        const bf16* col = zx + (long)(b*SEQ)*ZLD + 4096 + ch;
        bf16x4 v[11];
        #pragma unroll
        for (int k=0;k<11;k++){
            int t = t0 - 3 + k;
            if (t >= 0) v[k] = *(const bf16x4*)&col[(long)t*ZLD];
            else { v[k][0]=(bf16)0.f; v[k][1]=(bf16)0.f; v[k][2]=(bf16)0.f; v[k][3]=(bf16)0.f; }
        }
        #pragma unroll
        for (int j=0;j<8;j++){
            bf16x4 o;
            #pragma unroll
            for (int e=0;e<4;e++){
                float acc = bca[e] + (float)v[j][e]*tap[e].x + (float)v[j+1][e]*tap[e].y
                                   + (float)v[j+2][e]*tap[e].z + (float)v[j+3][e]*tap[e].w;
                o[e] = (bf16)silu_f(acc);
            }
            *(bf16x4*)&xc[(long)(b*SEQ + t0 + j)*CONVD + ch] = o;
        }
    } else {
        int wid  = ((blk-2560)*256 + threadIdx.x) >> 6;   // 0..2047
        int lane = threadIdx.x & 63;
        int h  = wid & 63, bc2 = wid >> 6;
        int b  = bc2 >> 4,  c  = bc2 & 15;
        float Ah   = -expf(A_log[h]);
        float bias = dt_bias[h];
        long tok0 = (long)(b*SEQ + c*CHUNKL);
        int l0 = lane*2;
        float d0 = softplus_f(dtf[(tok0+l0)*64 + h] + bias);
        float d1 = softplus_f(dtf[(tok0+l0+1)*64 + h] + bias);
        float s = (d0 + d1)*Ah;
        #pragma unroll
        for (int off=1; off<64; off<<=1){
            float t = __shfl_up(s, off, 64);
            if (lane >= off) s += t;
        }
        long base_h = (long)wid*128;
        float cs1 = s;
        float cs0 = s - d1*Ah;
        dtv[base_h+l0]   = d0;  dtv[base_h+l0+1]  = d1;
        dacs[base_h+l0]  = cs0; dacs[base_h+l0+1] = cs1;
        if (lane == 63) cdec[wid] = expf(cs1);
    }
}

// ---------------- CB via MFMA, per (b,c); side output BT[bc][n][l] ----------------
__global__ __launch_bounds__(256) void cb_mfma_kernel(const bf16* __restrict__ xc,
                                                      float* __restrict__ cb,
                                                      bf16* __restrict__ BT){
    __shared__ __align__(16) bf16 A1[128*LP];
    __shared__ __align__(16) bf16 B1[128*LP];
    int blk = blockIdx.x;  int b = blk>>4, c = blk&15;
    int tid = threadIdx.x;
    const int w = tid >> 6, lane = tid & 63;
    long tok0 = (long)(b*SEQ + c*CHUNKL);
    int l = tid>>1, n0 = (tid&1)*64;
    const bf16* crow = xc + tok0*CONVD + (long)l*CONVD;
    #pragma unroll
    for (int v=0;v<8;v++){
        *(bf16x8*)&A1[l*LP + n0 + v*8] = *(const bf16x8*)&crow[4224 + n0 + v*8];
        *(bf16x8*)&B1[l*LP + n0 + v*8] = *(const bf16x8*)&crow[4096 + n0 + v*8];
    }
    __syncthreads();
    f32x4v acc[2][8];
    #pragma unroll
    for (int mi=0;mi<2;mi++)
        #pragma unroll
        for (int ni=0;ni<8;ni++) acc[mi][ni] = {0.f,0.f,0.f,0.f};
    #pragma unroll
    for (int kk=0; kk<128; kk+=32){
        bf16x8 afr[2], bfr2[8];
        #pragma unroll
        for (int mi=0;mi<2;mi++)
            afr[mi] = *(const bf16x8*)&A1[(w*32 + mi*16 + (lane&15))*LP + kk + (lane>>4)*8];
        #pragma unroll
        for (int ni=0;ni<8;ni++)
            bfr2[ni] = *(const bf16x8*)&B1[(ni*16 + (lane&15))*LP + kk + (lane>>4)*8];
        #pragma unroll
        for (int mi=0;mi<2;mi++)
            #pragma unroll
            for (int ni=0;ni<8;ni++)
                acc[mi][ni] = __builtin_amdgcn_mfma_f32_16x16x32_bf16(afr[mi], bfr2[ni], acc[mi][ni], 0,0,0);
    }
    float* out = cb + (long)blk*16384;
    #pragma unroll
    for (int mi=0;mi<2;mi++)
        #pragma unroll
        for (int ni=0;ni<8;ni++){
            int r0 = w*32 + mi*16 + (lane>>4)*4;
            int c0 = ni*16 + (lane&15);
            #pragma unroll
            for (int j=0;j<4;j++) out[(long)(r0+j)*128 + c0] = acc[mi][ni][j];
        }
    // BT side output: BT[blk][n][l] = B[l][n]
    {
        int n = tid>>1, s0 = (tid&1)*64;
        bf16* btp = BT + (long)blk*16384 + (long)n*128 + s0;
        #pragma unroll
        for (int v=0;v<8;v++){
            bf16x8 o;
            #pragma unroll
            for (int e=0;e<8;e++) o[e] = B1[(s0+v*8+e)*LP + n];
            *(bf16x8*)&btp[v*8] = o;
        }
    }
}

// ---------------- states[p][n] via MFMA, per (b,c,h), bf16 out; B from BT (vector) ----------------
__global__ __launch_bounds__(256) void states_mfma_kernel(const bf16* __restrict__ xc,
                                                          const bf16* __restrict__ BT,
                                                          const float* __restrict__ dtv,
                                                          const float* __restrict__ dacs,
                                                          bf16* __restrict__ states){
    __shared__ __align__(16) bf16 A1[64*LP];
    __shared__ __align__(16) bf16 B1[128*LP];
    __shared__ float wgtl[128];
    int blk = blockIdx.x;
    int h = blk & 63, bc = blk >> 6;
    int b = bc >> 4, c = bc & 15;
    int tid = threadIdx.x;
    const int w = tid >> 6, lane = tid & 63;
    long tok0 = (long)(b*SEQ + c*CHUNKL);
    long base_h = (long)blk*128;
    float cs_last = dacs[base_h + 127];
    if (tid < 128) wgtl[tid] = dtv[base_h+tid] * expf(cs_last - dacs[base_h+tid]);
    __syncthreads();
    #pragma unroll
    for (int t=0;t<4;t++){
        int l = (tid>>3) + t*32;
        int p0 = (tid&7)*8;
        bf16x8 xv = *(const bf16x8*)&xc[(tok0+l)*CONVD + h*64 + p0];
        float wv = wgtl[l];
        #pragma unroll
        for (int e=0;e<8;e++) A1[(p0+e)*LP + l] = (bf16)((float)xv[e]*wv);
    }
    {
        int n = tid>>1, l0 = (tid&1)*64;
        const bf16* btp = BT + (long)bc*16384 + (long)n*128 + l0;
        #pragma unroll
        for (int v=0;v<8;v++)
            *(bf16x8*)&B1[n*LP + l0 + v*8] = *(const bf16x8*)&btp[v*8];
    }
    __syncthreads();
    f32x4v acc[8];
    #pragma unroll
    for (int ni=0;ni<8;ni++) acc[ni] = {0.f,0.f,0.f,0.f};
    #pragma unroll
    for (int kk=0; kk<128; kk+=32){
        bf16x8 afr = *(const bf16x8*)&A1[(w*16 + (lane&15))*LP + kk + (lane>>4)*8];
        #pragma unroll
        for (int ni=0;ni<8;ni++){
            bf16x8 bfr2 = *(const bf16x8*)&B1[(ni*16 + (lane&15))*LP + kk + (lane>>4)*8];
            acc[ni] = __builtin_amdgcn_mfma_f32_16x16x32_bf16(afr, bfr2, acc[ni], 0,0,0);
        }
    }
    bf16* out = states + (long)blk*8192;
    #pragma unroll
    for (int ni=0;ni<8;ni++){
        int p0 = w*16 + (lane>>4)*4;
        int n  = ni*16 + (lane&15);
        #pragma unroll
        for (int j=0;j<4;j++) out[(long)(p0+j)*128 + n] = (bf16)acc[ni][j];
    }
}

// ---------------- sequential chunk scan (bf16 in/out, f32 accum) ----------------
__global__ __launch_bounds__(256) void scan_kernel(const bf16* __restrict__ states,
                                                   const float* __restrict__ cdec,
                                                   bf16* __restrict__ hst){
    long gid = (long)blockIdx.x*256 + threadIdx.x;
    int n = gid & 127;
    int p = (gid >> 7) & 63;
    int h = (gid >> 13) & 63;
    int b = (int)(gid >> 19);
    float hrun = 0.f;
    for (int c=0;c<16;c++){
        long idx = ((((long)(b*16 + c)*64 + h)*64 + p)*128) + n;
        hst[idx] = (bf16)hrun;
        hrun = hrun * cdec[(b*16+c)*64 + h] + (float)states[idx];
    }
}

// ---------------- fused Y = P@u^T + (C*sdo)@hst^T ----------------
__global__ __launch_bounds__(256) void yfused_kernel(const bf16* __restrict__ xc,
                                                     const float* __restrict__ cb,
                                                     const bf16* __restrict__ hst,
                                                     const float* __restrict__ dtv,
                                                     const float* __restrict__ dacs,
                                                     bf16* __restrict__ Ybf){
    __shared__ __align__(16) bf16 A1[128*LP];
    __shared__ __align__(16) bf16 B1[64*LP];
    __shared__ float csl[128];
    int blk = blockIdx.x;
    int h = blk & 63, bc = blk >> 6;
    int b = bc >> 4, c = bc & 15;
    int tid = threadIdx.x;
    const int w = tid >> 6, lane = tid & 63;
    long tok0 = (long)(b*SEQ + c*CHUNKL);
    long base_h = (long)blk*128;
    if (tid < 128) csl[tid] = dacs[base_h + tid];
    __syncthreads();
    {
        int l = tid>>1, s0 = (tid&1)*64;
        float el = csl[l];
        const float* cbrow = cb + (long)bc*16384 + (long)l*128 + s0;
        int jend = l - s0; if (jend > 63) jend = 63;
        for (int j=0; j<=jend; j++)
            A1[l*LP + s0 + j] = (bf16)(cbrow[j]*expf(el - csl[s0+j]));
        for (int j=jend+1; j<64; j++)
            A1[l*LP + s0 + j] = (bf16)0.f;
    }
    #pragma unroll
    for (int t=0;t<4;t++){
        int s = (tid>>3) + t*32;
        int p0 = (tid&7)*8;
        bf16x8 xv = *(const bf16x8*)&xc[(tok0+s)*CONVD + h*64 + p0];
        float wv = dtv[base_h + s];
        #pragma unroll
        for (int e=0;e<8;e++) B1[(p0+e)*LP + s] = (bf16)((float)xv[e]*wv);
    }
    __syncthreads();
    f32x4v acc[2][4];
    #pragma unroll
    for (int mi=0;mi<2;mi++)
        #pragma unroll
        for (int ni=0;ni<4;ni++) acc[mi][ni] = {0.f,0.f,0.f,0.f};
    #pragma unroll
    for (int kk=0; kk<128; kk+=32){
        bf16x8 afr[2], bfr2[4];
        #pragma unroll
        for (int mi=0;mi<2;mi++)
            afr[mi] = *(const bf16x8*)&A1[(w*32 + mi*16 + (lane&15))*LP + kk + (lane>>4)*8];
        #pragma unroll
        for (int ni=0;ni<4;ni++)
            bfr2[ni] = *(const bf16x8*)&B1[(ni*16 + (lane&15))*LP + kk + (lane>>4)*8];
        #pragma unroll
        for (int mi=0;mi<2;mi++)
            #pragma unroll
            for (int ni=0;ni<4;ni++)
                acc[mi][ni] = __builtin_amdgcn_mfma_f32_16x16x32_bf16(afr[mi], bfr2[ni], acc[mi][ni], 0,0,0);
    }
    __syncthreads();
    {
        int l = tid>>1, n0 = (tid&1)*64;
        float e1 = expf(csl[l]);
        const bf16* crow = xc + (tok0+l)*CONVD + 4224;
        #pragma unroll
        for (int v=0;v<8;v++){
            bf16x8 cv = *(const bf16x8*)&crow[n0 + v*8];
            bf16x8 o;
            #pragma unroll
            for (int e=0;e<8;e++) o[e] = (bf16)((float)cv[e]*e1);
            *(bf16x8*)&A1[l*LP + n0 + v*8] = o;
        }
    }
    {
        int p = tid>>2, n0 = (tid&3)*32;
        const bf16* hrow = hst + (long)blk*8192 + (long)p*128 + n0;
        #pragma unroll
        for (int v=0;v<4;v++)
            *(bf16x8*)&B1[p*LP + n0 + v*8] = *(const bf16x8*)&hrow[v*8];
    }
    __syncthreads();
    #pragma unroll
    for (int kk=0; kk<128; kk+=32){
        bf16x8 afr[2], bfr2[4];
        #pragma unroll
        for (int mi=0;mi<2;mi++)
            afr[mi] = *(const bf16x8*)&A1[(w*32 + mi*16 + (lane&15))*LP + kk + (lane>>4)*8];
        #pragma unroll
        for (int ni=0;ni<4;ni++)
            bfr2[ni] = *(const bf16x8*)&B1[(ni*16 + (lane&15))*LP + kk + (lane>>4)*8];
        #pragma unroll
        for (int mi=0;mi<2;mi++)
            #pragma unroll
            for (int ni=0;ni<4;ni++)
                acc[mi][ni] = __builtin_amdgcn_mfma_f32_16x16x32_bf16(afr[mi], bfr2[ni], acc[mi][ni], 0,0,0);
    }
    #pragma unroll
    for (int mi=0;mi<2;mi++)
        #pragma unroll
        for (int ni=0;ni<4;ni++){
            int l0 = w*32 + mi*16 + (lane>>4)*4;
            int p  = ni*16 + (lane&15);
            #pragma unroll
            for (int j=0;j<4;j++)
                Ybf[(tok0 + l0 + j)*DI + h*64 + p] = (bf16)acc[mi][ni][j];
        }
}

// ---------------- gate (silu(z)) + D*x + RMSNorm + cast bf16 ----------------
__global__ __launch_bounds__(256) void gatenorm_kernel(const bf16* __restrict__ Ybf,
                                                       const bf16* __restrict__ zx,
                                                       const bf16* __restrict__ xc,
                                                       const float* __restrict__ Dp,
                                                       const float* __restrict__ nw,
                                                       bf16* __restrict__ ybn){
    __shared__ float red[4];
    int tok = blockIdx.x, tid = threadIdx.x;
    const bf16* yrow = Ybf + (long)tok*DI;
    const bf16* zrow = zx  + (long)tok*ZLD;
    const bf16* xrow = xc  + (long)tok*CONVD;
    float yg[16];
    float ss = 0.f;
    #pragma unroll
    for (int k=0;k<2;k++){
        int d = (tid + k*256)*8;
        bf16x8 yv = *(const bf16x8*)&yrow[d];
        bf16x8 zv = *(const bf16x8*)&zrow[d];
        bf16x8 xv = *(const bf16x8*)&xrow[d];
        float dh = Dp[d>>6];
        #pragma unroll
        for (int e=0;e<8;e++){
            float yy = (float)yv[e] + dh*(float)xv[e];
            float g = yy*silu_f((float)zv[e]);
            yg[k*8+e] = g;
            ss += g*g;
        }
    }
    #pragma unroll
    for (int off=32; off>0; off>>=1) ss += __shfl_down(ss, off, 64);
    if ((tid & 63) == 0) red[tid>>6] = ss;
    __syncthreads();
    float tot = red[0]+red[1]+red[2]+red[3];
    float scale = rsqrtf(tot/(float)DI + 1e-5f);
    #pragma unroll
    for (int k=0;k<2;k++){
        int d = (tid + k*256)*8;
        float4 w0 = *(const float4*)&nw[d];
        float4 w1 = *(const float4*)&nw[d+4];
        float wv[8] = {w0.x,w0.y,w0.z,w0.w,w1.x,w1.y,w1.z,w1.w};
        bf16x8 o;
        #pragma unroll
        for (int e=0;e<8;e++) o[e] = (bf16)(yg[k*8+e]*scale*wv[e]);
        *(bf16x8*)&ybn[(long)tok*DI + d] = o;
    }
}

// ---------------- launch ----------------
extern "C" void kernel_launch(void* const* d_in, const int* in_sizes, int n_in,
                              void* d_out, int out_size, void* d_ws, size_t ws_size,
                              hipStream_t stream){
    const float* hs      = (const float*)d_in[0];
    const float* W_in    = (const float*)d_in[1];
    const float* W_conv  = (const float*)d_in[2];
    const float* b_conv  = (const float*)d_in[3];
    const float* A_log   = (const float*)d_in[4];
    const float* Dp      = (const float*)d_in[5];
    const float* dt_bias = (const float*)d_in[6];
    const float* nw      = (const float*)d_in[7];
    const float* W_out   = (const float*)d_in[8];
    float* out = (float*)d_out;

    char* ws = (char*)d_ws;
    const size_t OFF_ZX    = 0;                    // bf16 [4096][8704]      71,303,168
    const size_t OFF_DTF   = 71303168;             // f32  [4096][64]         1,048,576
    const size_t OFF_XC    = 72351744;             // bf16 [4096][4352]      35,651,584
    const size_t OFF_DTV   = 108003328;            // f32                     1,048,576
    const size_t OFF_DACS  = 109051904;            //                         1,048,576
    const size_t OFF_CDEC  = 110100480;            // f32 [2048]                  8,192
    const size_t OFF_CB    = 110108672;            // f32 [32][128][128]      2,097,152
    const size_t OFF_SLOTA = 112205824;            // 67,108,864: hsb+winb -> states(bf16) -> Ybf
    const size_t OFF_SLOTB = 179314688;            // 33,554,432: BT -> hst(bf16) -> ybn
    const size_t OFF_WOUTB = 212869120;            // bf16 [2048][4096]      16,777,216

    bf16*  zx    = (bf16*)(ws + OFF_ZX);
    float* dtf   = (float*)(ws + OFF_DTF);
    bf16*  xc    = (bf16*)(ws + OFF_XC);
    float* dtv   = (float*)(ws + OFF_DTV);
    float* dacs  = (float*)(ws + OFF_DACS);
    float* cdec  = (float*)(ws + OFF_CDEC);
    float* cbuf  = (float*)(ws + OFF_CB);
    bf16*  hsb   = (bf16*)(ws + OFF_SLOTA);
    bf16*  winb  = (bf16*)(ws + OFF_SLOTA + 16777216);
    bf16*  states= (bf16*)(ws + OFF_SLOTA);
    bf16*  Ybf   = (bf16*)(ws + OFF_SLOTA);
    bf16*  BTb   = (bf16*)(ws + OFF_SLOTB);        // bf16 [32][128][128] (1MB)
    bf16*  hst   = (bf16*)(ws + OFF_SLOTB);        // written by scan (after states consumed BT)
    bf16*  ybn   = (bf16*)(ws + OFF_SLOTB);
    bf16*  woutb = (bf16*)(ws + OFF_WOUTB);

    cvt_all_kernel<<<33792, 256, 0, stream>>>(hs, W_in, W_out, hsb, winb, woutb);

    // GEMM1: 128x256 tiles, full N=8704 (34x32 = 1088 blocks, 2 blocks/CU)
    gemm1_kernel<<<1088, 512, 0, stream>>>(hsb, winb, zx, dtf, 34, 32, DMODEL);

    mid1_kernel<<<3072, 256, 0, stream>>>(zx, W_conv, b_conv, dtf, A_log, dt_bias,
                                          xc, dtv, dacs, cdec);
    cb_mfma_kernel<<<32, 256, 0, stream>>>(xc, cbuf, BTb);
    states_mfma_kernel<<<2048, 256, 0, stream>>>(xc, BTb, dtv, dacs, states);
    scan_kernel<<<4096, 256, 0, stream>>>(states, cdec, hst);
    yfused_kernel<<<2048, 256, 0, stream>>>(xc, cbuf, hst, dtv, dacs, Ybf);
    gatenorm_kernel<<<4096, 256, 0, stream>>>(Ybf, zx, xc, Dp, nw, ybn);

    // GEMM2: [4096,4096] x [2048,4096]^T -> out f32 direct (256x128 tiles, 1 round)
    gemm256x128_kernel<<<256, 512, 0, stream>>>(ybn, woutb, out, 16, 16, DI, DMODEL);
}

// Round 16
// 381.138 us; speedup vs baseline: 1.0692x; 1.0692x over previous
//
#include <hip/hip_runtime.h>
#include <hip/hip_bf16.h>
#include <stdint.h>

typedef __bf16 bf16;
typedef __bf16 bf16x8 __attribute__((ext_vector_type(8)));
typedef __bf16 bf16x4 __attribute__((ext_vector_type(4)));
typedef float f32x4v __attribute__((ext_vector_type(4)));

#define SEQ    2048
#define DMODEL 2048
#define DI     4096
#define NH     64
#define PDIM   64
#define CHUNKL 128
#define NCH    16
#define CONVD  4352
#define DPROJ  8512
#define ZLD    8704   // zxbcdt leading dim, padded to 34*256
#define NTOK   4096
#define LP     136    // padded LDS leading dim for middle kernels

__device__ __forceinline__ float sigmoid_f(float x){ return 1.f/(1.f+expf(-x)); }
__device__ __forceinline__ float silu_f(float x){ return x*sigmoid_f(x); }
__device__ __forceinline__ float softplus_f(float x){ return x > 20.f ? x : log1pf(expf(x)); }

// ---------------- fused conversions: hs->bf16 | W_in->bf16 padded | W_out->bf16 ----------------
__global__ __launch_bounds__(256) void cvt_all_kernel(const float* __restrict__ hs,
                                                      const float* __restrict__ W_in,
                                                      const float* __restrict__ W_out,
                                                      bf16* __restrict__ hsb,
                                                      bf16* __restrict__ winb,
                                                      bf16* __restrict__ woutb){
    int blk = blockIdx.x;
    if (blk < 8192){
        int i = (blk*256 + threadIdx.x)*4;
        float4 v = *(const float4*)&hs[i];
        bf16x4 o; o[0]=(bf16)v.x; o[1]=(bf16)v.y; o[2]=(bf16)v.z; o[3]=(bf16)v.w;
        *(bf16x4*)&hsb[i] = o;
    } else if (blk < 25600){
        int i = ((blk-8192)*256 + threadIdx.x)*4;   // over 8704*2048
        int r = i >> 11;
        bf16x4 o;
        if (r < DPROJ){
            float4 v = *(const float4*)&W_in[i];
            o[0]=(bf16)v.x; o[1]=(bf16)v.y; o[2]=(bf16)v.z; o[3]=(bf16)v.w;
        } else {
            o[0]=(bf16)0.f; o[1]=(bf16)0.f; o[2]=(bf16)0.f; o[3]=(bf16)0.f;
        }
        *(bf16x4*)&winb[i] = o;
    } else {
        int i = ((blk-25600)*256 + threadIdx.x)*4;
        float4 v = *(const float4*)&W_out[i];
        bf16x4 o; o[0]=(bf16)v.x; o[1]=(bf16)v.y; o[2]=(bf16)v.z; o[3]=(bf16)v.w;
        *(bf16x4*)&woutb[i] = o;
    }
}

// ============ shared GEMM fragment macros ============
#define READ_AF(BUFP, QM, AF)                                                          \
    {                                                                                  \
        _Pragma("unroll")                                                              \
        for (int i=0;i<4;i++)                                                          \
            _Pragma("unroll")                                                          \
            for (int k2=0;k2<2;k2++)                                                   \
                AF[i][k2] = *(const bf16x8*)&(BUFP)[aoff[i][k2] + (QM)*8192];          \
    }

#define READ_B(BUFP, QN, BFR)                                                          \
    {                                                                                  \
        _Pragma("unroll")                                                              \
        for (int nf=0;nf<2;nf++)                                                       \
            _Pragma("unroll")                                                          \
            for (int k2=0;k2<2;k2++)                                                   \
                BFR[nf][k2] = *(const bf16x8*)&(BUFP)[boff[nf][k2] + (QN)*8192];       \
    }

#define MMA_QA(AF, QM, QN, BFR)                                                        \
    {                                                                                  \
        __builtin_amdgcn_s_setprio(1);                                                 \
        _Pragma("unroll")                                                              \
        for (int i=0;i<4;i++)                                                          \
            _Pragma("unroll")                                                          \
            for (int nf=0;nf<2;nf++)                                                   \
                _Pragma("unroll")                                                      \
                for (int k2=0;k2<2;k2++)                                               \
                    acc[(QM)*4+i][(QN)*2+nf] = __builtin_amdgcn_mfma_f32_16x16x32_bf16( \
                        AF[i][k2], BFR[nf][k2], acc[(QM)*4+i][(QN)*2+nf], 0,0,0);      \
        __builtin_amdgcn_s_setprio(0);                                                 \
    }

#define SBAR() do { __builtin_amdgcn_sched_barrier(0);                                 \
                    __builtin_amdgcn_s_barrier();                                      \
                    asm volatile("s_waitcnt lgkmcnt(0)" ::: "memory");                 \
                    __builtin_amdgcn_sched_barrier(0); } while(0)

// ============ GEMM1: bulk 256x256 merged-read 2-phase (bid>=256) + tail (bid<256) ============
// Race-free: B1's vmcnt retires tile t's 8 loads before any read; all 32 fragment
// reads issue together under one lgkmcnt(0); PhB has no reads. Stages into consumed
// regions sit after barriers that follow those reads.
__global__ __launch_bounds__(512) void gemm1_kernel(const bf16* __restrict__ A,
                                                    const bf16* __restrict__ Bmat,
                                                    bf16* __restrict__ Cz,
                                                    float* __restrict__ tpart,
                                                    int NXB, int NYB, int K){
    __shared__ __align__(16) bf16 lds[2][2*16384];   // [buf][A(16384) | B(16384)]
    const int tid  = threadIdx.x;
    const int w    = tid >> 6;
    const int lane = tid & 63;
    const int wm   = w >> 2, wn = w & 3;
    const int bid  = blockIdx.x;

    int aoff[4][2], boff[2][2];
    #pragma unroll
    for (int i=0;i<4;i++)
        #pragma unroll
        for (int k2=0;k2<2;k2++){
            int ra0 = wm*64 + i*16 + (lane&15);
            int slot = (k2*4 + (lane>>4)) ^ (ra0&7);
            aoff[i][k2] = ra0*64 + slot*8;
        }
    #pragma unroll
    for (int nf=0;nf<2;nf++)
        #pragma unroll
        for (int k2=0;k2<2;k2++){
            int rb0 = wn*32 + nf*16 + (lane&15);
            int slot = (k2*4 + (lane>>4)) ^ (rb0&7);
            boff[nf][k2] = 16384 + rb0*64 + slot*8;
        }
    const int er = (lane>>4)*4, ec = lane&15;

    if (bid < 256){
        // ================= tail: 256x128 tile, split-K=4, KT=8 (syncthreads dbuf) =================
        int kz  = bid >> 6;
        int t64 = bid & 63;
        const int tn2 = 8192 + (t64 & 3)*128;
        const int tm2 = (t64 >> 2)*256;
        const int kt0 = kz*8;

        const bf16* srcA2[2][2];
        const bf16* srcB2[2];
        #pragma unroll
        for (int r0h=0;r0h<2;r0h++)
            #pragma unroll
            for (int i=0;i<2;i++){
                int lr = r0h*128 + i*64 + (tid>>3);
                int growA = tm2 + ((lr>>6)&1)*128 + (lr>>7)*64 + (lr&63);
                int gslot = (tid&7) ^ (lr&7);
                srcA2[r0h][i] = A + (long)growA*K + gslot*8;
            }
        #pragma unroll
        for (int i=0;i<2;i++){
            int lr = i*64 + (tid>>3);
            int gslot = (tid&7) ^ (lr&7);
            srcB2[i] = Bmat + (long)(tn2 + lr)*K + gslot*8;
        }
        auto stA = [&](int buf, int t, int r0h){
            long koff = (long)(kt0 + t)*64;
            #pragma unroll
            for (int i=0;i<2;i++){
                bf16* dst = &lds[buf][0] + (size_t)(r0h*128 + i*64 + w*8)*64;
                __builtin_amdgcn_global_load_lds(
                    (const __attribute__((address_space(1))) void*)(srcA2[r0h][i] + koff),
                    (__attribute__((address_space(3))) void*)dst, 16, 0, 0);
            }
        };
        auto stB = [&](int buf, int t){
            long koff = (long)(kt0 + t)*64;
            #pragma unroll
            for (int i=0;i<2;i++){
                bf16* dst = &lds[buf][16384] + (size_t)(i*64 + w*8)*64;
                __builtin_amdgcn_global_load_lds(
                    (const __attribute__((address_space(1))) void*)(srcB2[i] + koff),
                    (__attribute__((address_space(3))) void*)dst, 16, 0, 0);
            }
        };

        f32x4v acc2[8][2];
        #pragma unroll
        for (int i=0;i<8;i++)
            #pragma unroll
            for (int j=0;j<2;j++) acc2[i][j] = {0.f,0.f,0.f,0.f};
        bf16x8 af[4][2], af1[4][2], bfr0[2][2];

        stA(0,0,0); stA(0,0,1); stB(0,0);
        __syncthreads();
        int cur = 0;
        for (int t=0; t<8; ++t){
            int nxt = cur ^ 1;
            const bf16* bufc = &lds[cur][0];
            if (t+1 < 8){ stA(nxt,t+1,0); stA(nxt,t+1,1); stB(nxt,t+1); }
            READ_AF(bufc, 0, af)
            READ_AF(bufc, 1, af1)
            READ_B(bufc, 0, bfr0)
            #pragma unroll
            for (int i=0;i<4;i++)
                #pragma unroll
                for (int nf=0;nf<2;nf++)
                    #pragma unroll
                    for (int k2=0;k2<2;k2++)
                        acc2[i][nf] = __builtin_amdgcn_mfma_f32_16x16x32_bf16(
                            af[i][k2], bfr0[nf][k2], acc2[i][nf], 0,0,0);
            #pragma unroll
            for (int i=0;i<4;i++)
                #pragma unroll
                for (int nf=0;nf<2;nf++)
                    #pragma unroll
                    for (int k2=0;k2<2;k2++)
                        acc2[4+i][nf] = __builtin_amdgcn_mfma_f32_16x16x32_bf16(
                            af1[i][k2], bfr0[nf][k2], acc2[4+i][nf], 0,0,0);
            __syncthreads();   // drains vmcnt(0)+lgkmcnt(0): safe dbuf boundary
            cur = nxt;
        }
        #pragma unroll
        for (int mi=0;mi<8;mi++)
            #pragma unroll
            for (int nf=0;nf<2;nf++){
                long r0 = tm2 + wm*128 + mi*16 + er;
                int  c0 = tn2 + wn*32 + nf*16 + ec;
                #pragma unroll
                for (int j=0;j<4;j++)
                    tpart[((long)kz*4096 + (r0+j))*512 + (c0 - 8192)] = acc2[mi][nf][j];
            }
        return;
    }

    // ================= bulk: 256x256 merged-read 2-phase =================
    int bid2 = bid - 256;             // 0..511
    int wg   = (bid2 & 7)*64 + (bid2 >> 3);
    const int SW = 8;
    int sup = wg / (SW*NYB);
    int rr  = wg % (SW*NYB);
    int x0  = sup*SW;
    int wl  = (NXB - x0 < SW) ? (NXB - x0) : SW;
    int x   = x0 + rr % wl;
    int y   = rr / wl;
    const int tm = y*256, tn = x*256;
    const int KT = K >> 6;

    f32x4v acc[8][4];
    #pragma unroll
    for (int i=0;i<8;i++)
        #pragma unroll
        for (int j=0;j<4;j++) acc[i][j] = {0.f,0.f,0.f,0.f};
    bf16x8 af[4][2], af1[4][2];
    bf16x8 bfr0[2][2], bfr1[2][2];

    const bf16* srcA[2][2];
    const bf16* srcB[2][2];
    #pragma unroll
    for (int r0h=0;r0h<2;r0h++)
        #pragma unroll
        for (int i=0;i<2;i++){
            int lr = r0h*128 + i*64 + (tid>>3);
            int growA = tm + ((lr>>6)&1)*128 + (lr>>7)*64 + (lr&63);
            int growB = tn + ((lr>>5)&3)*64 + (lr>>7)*32 + (lr&31);
            int gslot = (tid&7) ^ (lr&7);
            srcA[r0h][i] = A + (long)growA*K + gslot*8;
            srcB[r0h][i] = Bmat + (long)growB*K + gslot*8;
        }

    auto stageA = [&](int buf, int t, int r0h){
        long koff = (long)t*64;
        #pragma unroll
        for (int i=0;i<2;i++){
            bf16* dst = &lds[buf][0] + (size_t)(r0h*128 + i*64 + w*8)*64;
            __builtin_amdgcn_global_load_lds(
                (const __attribute__((address_space(1))) void*)(srcA[r0h][i] + koff),
                (__attribute__((address_space(3))) void*)dst, 16, 0, 0);
        }
    };
    auto stageB = [&](int buf, int t, int r0h){
        long koff = (long)t*64;
        #pragma unroll
        for (int i=0;i<2;i++){
            bf16* dst = &lds[buf][16384] + (size_t)(r0h*128 + i*64 + w*8)*64;
            __builtin_amdgcn_global_load_lds(
                (const __attribute__((address_space(1))) void*)(srcB[r0h][i] + koff),
                (__attribute__((address_space(3))) void*)dst, 16, 0, 0);
        }
    };

    // ---- prologue: tile0 {A0,B0,B1,A1} (8 loads), tile1 {A0,B0,B1} (6 loads) ----
    stageA(0, 0, 0); stageB(0, 0, 0); stageB(0, 0, 1); stageA(0, 0, 1);
    if (KT > 1){ stageA(1, 1, 0); stageB(1, 1, 0); stageB(1, 1, 1); }

    int cur = 0;
    for (int t = 0; t < KT; ++t){
        int nxt = cur ^ 1;
        const bf16* bufc = &lds[cur][0];
        // ---- B1: vmcnt retires tile t's 8 loads, then barrier ----
        if (t+1 < KT){ asm volatile("s_waitcnt vmcnt(6)" ::: "memory"); }
        else         { asm volatile("s_waitcnt vmcnt(0)" ::: "memory"); }
        __builtin_amdgcn_sched_barrier(0);
        __builtin_amdgcn_s_barrier();
        __builtin_amdgcn_sched_barrier(0);
        if (t+1 < KT) stageA(nxt, t+1, 1);   // A1(t+1): region read last tile, barrier passed
        // ---- merged reads: all 32 fragment ds_reads for tile t ----
        READ_AF(bufc, 0, af)
        READ_AF(bufc, 1, af1)
        READ_B(bufc, 0, bfr0)
        READ_B(bufc, 1, bfr1)
        asm volatile("s_waitcnt lgkmcnt(0)" ::: "memory");
        __builtin_amdgcn_sched_barrier(0);
        // ---- PhA MMA ----
        MMA_QA(af, 0, 0, bfr0)
        MMA_QA(af, 0, 1, bfr1)
        __builtin_amdgcn_sched_barrier(0);
        // ---- B2: barrier (all reads complete block-wide) ----
        __builtin_amdgcn_s_barrier();
        __builtin_amdgcn_sched_barrier(0);
        if (t+2 < KT){ stageA(cur, t+2, 0); stageB(cur, t+2, 0); stageB(cur, t+2, 1); }
        // ---- PhB MMA (no reads) ----
        MMA_QA(af1, 1, 0, bfr0)
        MMA_QA(af1, 1, 1, bfr1)
        __builtin_amdgcn_sched_barrier(0);
        cur = nxt;
    }

    #pragma unroll
    for (int mi=0;mi<8;mi++)
        #pragma unroll
        for (int ni=0;ni<4;ni++){
            long r0 = tm + wm*128 + mi*16 + er;
            int  c0 = tn + wn*64 + ni*16 + ec;
            #pragma unroll
            for (int j=0;j<4;j++)
                Cz[(r0+j)*ZLD + c0] = (bf16)acc[mi][ni][j];
        }
}

// ============ 256x128 triple-buffered bf16 GEMM (GEMM2): merged-read ============
__global__ __launch_bounds__(512) void gemm256x128_kernel(const bf16* __restrict__ A,
                                                          const bf16* __restrict__ Bmat,
                                                          float* __restrict__ C,
                                                          int NXB, int NYB, int K, int ldc){
    __shared__ __align__(16) bf16 lds[3][24576];   // [buf][A(16384) | B(8192)]
    const int tid  = threadIdx.x;
    const int w    = tid >> 6;
    const int lane = tid & 63;
    const int wm   = w >> 2, wn = w & 3;

    int bid = blockIdx.x, nb = gridDim.x;
    int wg = (bid & 7)*(nb >> 3) + (bid >> 3);
    const int SW = 8;
    int sup = wg / (SW*NYB);
    int rr  = wg % (SW*NYB);
    int x0  = sup*SW;
    int wl  = (NXB - x0 < SW) ? (NXB - x0) : SW;
    int x   = x0 + rr % wl;
    int y   = rr / wl;
    const int tm = y*256, tn = x*128;
    const int KT = K >> 6;

    f32x4v acc[8][2];
    #pragma unroll
    for (int i=0;i<8;i++)
        #pragma unroll
        for (int j=0;j<2;j++) acc[i][j] = {0.f,0.f,0.f,0.f};
    bf16x8 af[4][2], af1[4][2];
    bf16x8 bfr[2][2];

    const bf16* srcA[2][2];
    const bf16* srcB[2];
    #pragma unroll
    for (int r0h=0;r0h<2;r0h++)
        #pragma unroll
        for (int i=0;i<2;i++){
            int lr = r0h*128 + i*64 + (tid>>3);
            int growA = tm + ((lr>>6)&1)*128 + (lr>>7)*64 + (lr&63);
            int gslot = (tid&7) ^ (lr&7);
            srcA[r0h][i] = A + (long)growA*K + gslot*8;
        }
    #pragma unroll
    for (int i=0;i<2;i++){
        int lr = i*64 + (tid>>3);
        int gslot = (tid&7) ^ (lr&7);
        srcB[i] = Bmat + (long)(tn + lr)*K + gslot*8;
    }
    int aoff[4][2], boff[2][2];
    #pragma unroll
    for (int i=0;i<4;i++)
        #pragma unroll
        for (int k2=0;k2<2;k2++){
            int ra0 = wm*64 + i*16 + (lane&15);
            int slot = (k2*4 + (lane>>4)) ^ (ra0&7);
            aoff[i][k2] = ra0*64 + slot*8;
        }
    #pragma unroll
    for (int nf=0;nf<2;nf++)
        #pragma unroll
        for (int k2=0;k2<2;k2++){
            int rb0 = wn*32 + nf*16 + (lane&15);
            int slot = (k2*4 + (lane>>4)) ^ (rb0&7);
            boff[nf][k2] = 16384 + rb0*64 + slot*8;
        }

    auto stageA = [&](int buf, int t, int r0h){
        long koff = (long)t*64;
        #pragma unroll
        for (int i=0;i<2;i++){
            bf16* dst = &lds[buf][0] + (size_t)(r0h*128 + i*64 + w*8)*64;
            __builtin_amdgcn_global_load_lds(
                (const __attribute__((address_space(1))) void*)(srcA[r0h][i] + koff),
                (__attribute__((address_space(3))) void*)dst, 16, 0, 0);
        }
    };
    auto stageB = [&](int buf, int t){
        long koff = (long)t*64;
        #pragma unroll
        for (int i=0;i<2;i++){
            bf16* dst = &lds[buf][16384] + (size_t)(i*64 + w*8)*64;
            __builtin_amdgcn_global_load_lds(
                (const __attribute__((address_space(1))) void*)(srcB[i] + koff),
                (__attribute__((address_space(3))) void*)dst, 16, 0, 0);
        }
    };

    stageA(0, 0, 0); stageA(0, 0, 1); stageB(0, 0);
    if (KT > 1){ stageA(1, 1, 0); stageA(1, 1, 1); stageB(1, 1); }
    asm volatile("s_waitcnt vmcnt(6)" ::: "memory");   // tile-0 A+B complete
    __builtin_amdgcn_s_barrier();

    int cur = 0;
    for (int t = 0; t < KT; ++t){
        int stb = cur + 2; if (stb >= 3) stb -= 3;
        const bf16* bufc = &lds[cur][0];
        READ_AF(bufc, 0, af)
        READ_AF(bufc, 1, af1)
        READ_B(bufc, 0, bfr)
        if (t+2 < KT){ stageA(stb, t+2, 0); stageA(stb, t+2, 1); }
        SBAR();
        MMA_QA(af, 0, 0, bfr)
        if (t+2 < KT){
            stageB(stb, t+2);
            asm volatile("s_waitcnt vmcnt(6)" ::: "memory");
        } else {
            asm volatile("s_waitcnt vmcnt(0)" ::: "memory");
        }
        SBAR();
        MMA_QA(af1, 1, 0, bfr)
        cur = (cur == 2) ? 0 : cur + 1;
    }

    const int er = (lane>>4)*4, ec = lane&15;
    #pragma unroll
    for (int mi=0;mi<8;mi++)
        #pragma unroll
        for (int ni=0;ni<2;ni++){
            long r0 = tm + wm*128 + mi*16 + er;
            int  c0 = tn + wn*32 + ni*16 + ec;
            #pragma unroll
            for (int j=0;j<4;j++)
                C[(r0+j)*ldc + c0] = acc[mi][ni][j];
        }
}

// ---------------- GEMM1 tail reduce: 4 f32 partials -> zx bf16 + dtf f32 ----------------
__global__ __launch_bounds__(256) void tailreduce_kernel(const float* __restrict__ p,
                                                         bf16* __restrict__ zx,
                                                         float* __restrict__ dtf){
    long i = ((long)blockIdx.x*256 + threadIdx.x)*4;   // over 4096*512
    int r = (int)(i >> 9);
    int c = (int)(i & 511);
    const long Q = (long)4096*512;
    float4 a  = *(const float4*)&p[i];
    float4 b  = *(const float4*)&p[i+Q];
    float4 cc = *(const float4*)&p[i+2*Q];
    float4 d  = *(const float4*)&p[i+3*Q];
    float s0 = a.x+b.x+cc.x+d.x, s1 = a.y+b.y+cc.y+d.y;
    float s2 = a.z+b.z+cc.z+d.z, s3 = a.w+b.w+cc.w+d.w;
    bf16x4 o; o[0]=(bf16)s0; o[1]=(bf16)s1; o[2]=(bf16)s2; o[3]=(bf16)s3;
    *(bf16x4*)&zx[(long)r*ZLD + 8192 + c] = o;
    int col = 8192 + c;
    float sv[4] = {s0,s1,s2,s3};
    #pragma unroll
    for (int j=0;j<4;j++){
        int cj = col + j;
        if (cj >= 8448 && cj < 8512) dtf[(long)r*64 + (cj-8448)] = sv[j];
    }
}

// ---------------- merged: conv (blocks 0..2559) + dtcum (blocks 2560..3071) ----------------
__global__ __launch_bounds__(256) void mid1_kernel(const bf16* __restrict__ zx,
                                                   const float* __restrict__ Wc,
                                                   const float* __restrict__ bc,
                                                   const float* __restrict__ dtf,
                                                   const float* __restrict__ A_log,
                                                   const float* __restrict__ dt_bias,
                                                   bf16* __restrict__ xc,
                                                   float* __restrict__ dtv,
                                                   float* __restrict__ dacs,
                                                   float* __restrict__ cdec){
    int blk = blockIdx.x;
    if (blk < 2560){
        int by = blk/5, bx = blk%5;
        int c4 = bx*256 + threadIdx.x;
        if (c4 >= 1088) return;
        int ch = c4*4;
        int b = by >> 8, t0 = (by & 255)*8;
        float4 tap[4];
        #pragma unroll
        for (int e=0;e<4;e++) tap[e] = *(const float4*)&Wc[(ch+e)*4];
        float4 bq = *(const float4*)&bc[ch];
        float bca[4] = {bq.x, bq.y, bq.z, bq.w};
        const bf16* col = zx + (long)(b*SEQ)*ZLD + 4096 + ch;
        bf16x4 v[11];
        #pragma unroll
        for (int k=0;k<11;k++){
            int t = t0 - 3 + k;
            if (t >= 0) v[k] = *(const bf16x4*)&col[(long)t*ZLD];
            else { v[k][0]=(bf16)0.f; v[k][1]=(bf16)0.f; v[k][2]=(bf16)0.f; v[k][3]=(bf16)0.f; }
        }
        #pragma unroll
        for (int j=0;j<8;j++){
            bf16x4 o;
            #pragma unroll
            for (int e=0;e<4;e++){
                float acc = bca[e] + (float)v[j][e]*tap[e].x + (float)v[j+1][e]*tap[e].y
                                   + (float)v[j+2][e]*tap[e].z + (float)v[j+3][e]*tap[e].w;
                o[e] = (bf16)silu_f(acc);
            }
            *(bf16x4*)&xc[(long)(b*SEQ + t0 + j)*CONVD + ch] = o;
        }
    } else {
        int wid  = ((blk-2560)*256 + threadIdx.x) >> 6;   // 0..2047
        int lane = threadIdx.x & 63;
        int h  = wid & 63, bc2 = wid >> 6;
        int b  = bc2 >> 4,  c  = bc2 & 15;
        float Ah   = -expf(A_log[h]);
        float bias = dt_bias[h];
        long tok0 = (long)(b*SEQ + c*CHUNKL);
        int l0 = lane*2;
        float d0 = softplus_f(dtf[(tok0+l0)*64 + h] + bias);
        float d1 = softplus_f(dtf[(tok0+l0+1)*64 + h] + bias);
        float s = (d0 + d1)*Ah;
        #pragma unroll
        for (int off=1; off<64; off<<=1){
            float t = __shfl_up(s, off, 64);
            if (lane >= off) s += t;
        }
        long base_h = (long)wid*128;
        float cs1 = s;
        float cs0 = s - d1*Ah;
        dtv[base_h+l0]   = d0;  dtv[base_h+l0+1]  = d1;
        dacs[base_h+l0]  = cs0; dacs[base_h+l0+1] = cs1;
        if (lane == 63) cdec[wid] = expf(cs1);
    }
}

// ---------------- CB via MFMA, per (b,c); side output BT[bc][n][l] ----------------
__global__ __launch_bounds__(256) void cb_mfma_kernel(const bf16* __restrict__ xc,
                                                      float* __restrict__ cb,
                                                      bf16* __restrict__ BT){
    __shared__ __align__(16) bf16 A1[128*LP];
    __shared__ __align__(16) bf16 B1[128*LP];
    int blk = blockIdx.x;  int b = blk>>4, c = blk&15;
    int tid = threadIdx.x;
    const int w = tid >> 6, lane = tid & 63;
    long tok0 = (long)(b*SEQ + c*CHUNKL);
    int l = tid>>1, n0 = (tid&1)*64;
    const bf16* crow = xc + tok0*CONVD + (long)l*CONVD;
    #pragma unroll
    for (int v=0;v<8;v++){
        *(bf16x8*)&A1[l*LP + n0 + v*8] = *(const bf16x8*)&crow[4224 + n0 + v*8];
        *(bf16x8*)&B1[l*LP + n0 + v*8] = *(const bf16x8*)&crow[4096 + n0 + v*8];
    }
    __syncthreads();
    f32x4v acc[2][8];
    #pragma unroll
    for (int mi=0;mi<2;mi++)
        #pragma unroll
        for (int ni=0;ni<8;ni++) acc[mi][ni] = {0.f,0.f,0.f,0.f};
    #pragma unroll
    for (int kk=0; kk<128; kk+=32){
        bf16x8 afr[2], bfr2[8];
        #pragma unroll
        for (int mi=0;mi<2;mi++)
            afr[mi] = *(const bf16x8*)&A1[(w*32 + mi*16 + (lane&15))*LP + kk + (lane>>4)*8];
        #pragma unroll
        for (int ni=0;ni<8;ni++)
            bfr2[ni] = *(const bf16x8*)&B1[(ni*16 + (lane&15))*LP + kk + (lane>>4)*8];
        #pragma unroll
        for (int mi=0;mi<2;mi++)
            #pragma unroll
            for (int ni=0;ni<8;ni++)
                acc[mi][ni] = __builtin_amdgcn_mfma_f32_16x16x32_bf16(afr[mi], bfr2[ni], acc[mi][ni], 0,0,0);
    }
    float* out = cb + (long)blk*16384;
    #pragma unroll
    for (int mi=0;mi<2;mi++)
        #pragma unroll
        for (int ni=0;ni<8;ni++){
            int r0 = w*32 + mi*16 + (lane>>4)*4;
            int c0 = ni*16 + (lane&15);
            #pragma unroll
            for (int j=0;j<4;j++) out[(long)(r0+j)*128 + c0] = acc[mi][ni][j];
        }
    // BT side output: BT[blk][n][l] = B[l][n]
    {
        int n = tid>>1, s0 = (tid&1)*64;
        bf16* btp = BT + (long)blk*16384 + (long)n*128 + s0;
        #pragma unroll
        for (int v=0;v<8;v++){
            bf16x8 o;
            #pragma unroll
            for (int e=0;e<8;e++) o[e] = B1[(s0+v*8+e)*LP + n];
            *(bf16x8*)&btp[v*8] = o;
        }
    }
}

// ---------------- states[p][n] via MFMA, per (b,c,h), bf16 out; B from BT (vector) ----------------
__global__ __launch_bounds__(256) void states_mfma_kernel(const bf16* __restrict__ xc,
                                                          const bf16* __restrict__ BT,
                                                          const float* __restrict__ dtv,
                                                          const float* __restrict__ dacs,
                                                          bf16* __restrict__ states){
    __shared__ __align__(16) bf16 A1[64*LP];
    __shared__ __align__(16) bf16 B1[128*LP];
    __shared__ float wgtl[128];
    int blk = blockIdx.x;
    int h = blk & 63, bc = blk >> 6;
    int b = bc >> 4, c = bc & 15;
    int tid = threadIdx.x;
    const int w = tid >> 6, lane = tid & 63;
    long tok0 = (long)(b*SEQ + c*CHUNKL);
    long base_h = (long)blk*128;
    float cs_last = dacs[base_h + 127];
    if (tid < 128) wgtl[tid] = dtv[base_h+tid] * expf(cs_last - dacs[base_h+tid]);
    __syncthreads();
    #pragma unroll
    for (int t=0;t<4;t++){
        int l = (tid>>3) + t*32;
        int p0 = (tid&7)*8;
        bf16x8 xv = *(const bf16x8*)&xc[(tok0+l)*CONVD + h*64 + p0];
        float wv = wgtl[l];
        #pragma unroll
        for (int e=0;e<8;e++) A1[(p0+e)*LP + l] = (bf16)((float)xv[e]*wv);
    }
    {
        int n = tid>>1, l0 = (tid&1)*64;
        const bf16* btp = BT + (long)bc*16384 + (long)n*128 + l0;
        #pragma unroll
        for (int v=0;v<8;v++)
            *(bf16x8*)&B1[n*LP + l0 + v*8] = *(const bf16x8*)&btp[v*8];
    }
    __syncthreads();
    f32x4v acc[8];
    #pragma unroll
    for (int ni=0;ni<8;ni++) acc[ni] = {0.f,0.f,0.f,0.f};
    #pragma unroll
    for (int kk=0; kk<128; kk+=32){
        bf16x8 afr = *(const bf16x8*)&A1[(w*16 + (lane&15))*LP + kk + (lane>>4)*8];
        #pragma unroll
        for (int ni=0;ni<8;ni++){
            bf16x8 bfr2 = *(const bf16x8*)&B1[(ni*16 + (lane&15))*LP + kk + (lane>>4)*8];
            acc[ni] = __builtin_amdgcn_mfma_f32_16x16x32_bf16(afr, bfr2, acc[ni], 0,0,0);
        }
    }
    bf16* out = states + (long)blk*8192;
    #pragma unroll
    for (int ni=0;ni<8;ni++){
        int p0 = w*16 + (lane>>4)*4;
        int n  = ni*16 + (lane&15);
        #pragma unroll
        for (int j=0;j<4;j++) out[(long)(p0+j)*128 + n] = (bf16)acc[ni][j];
    }
}

// ---------------- sequential chunk scan (bf16 in/out, f32 accum) ----------------
__global__ __launch_bounds__(256) void scan_kernel(const bf16* __restrict__ states,
                                                   const float* __restrict__ cdec,
                                                   bf16* __restrict__ hst){
    long gid = (long)blockIdx.x*256 + threadIdx.x;
    int n = gid & 127;
    int p = (gid >> 7) & 63;
    int h = (gid >> 13) & 63;
    int b = (int)(gid >> 19);
    float hrun = 0.f;
    for (int c=0;c<16;c++){
        long idx = ((((long)(b*16 + c)*64 + h)*64 + p)*128) + n;
        hst[idx] = (bf16)hrun;
        hrun = hrun * cdec[(b*16+c)*64 + h] + (float)states[idx];
    }
}

// ---------------- fused Y = P@u^T + (C*sdo)@hst^T ----------------
__global__ __launch_bounds__(256) void yfused_kernel(const bf16* __restrict__ xc,
                                                     const float* __restrict__ cb,
                                                     const bf16* __restrict__ hst,
                                                     const float* __restrict__ dtv,
                                                     const float* __restrict__ dacs,
                                                     bf16* __restrict__ Ybf){
    __shared__ __align__(16) bf16 A1[128*LP];
    __shared__ __align__(16) bf16 B1[64*LP];
    __shared__ float csl[128];
    int blk = blockIdx.x;
    int h = blk & 63, bc = blk >> 6;
    int b = bc >> 4, c = bc & 15;
    int tid = threadIdx.x;
    const int w = tid >> 6, lane = tid & 63;
    long tok0 = (long)(b*SEQ + c*CHUNKL);
    long base_h = (long)blk*128;
    if (tid < 128) csl[tid] = dacs[base_h + tid];
    __syncthreads();
    {
        int l = tid>>1, s0 = (tid&1)*64;
        float el = csl[l];
        const float* cbrow = cb + (long)bc*16384 + (long)l*128 + s0;
        int jend = l - s0; if (jend > 63) jend = 63;
        for (int j=0; j<=jend; j++)
            A1[l*LP + s0 + j] = (bf16)(cbrow[j]*expf(el - csl[s0+j]));
        for (int j=jend+1; j<64; j++)
            A1[l*LP + s0 + j] = (bf16)0.f;
    }
    #pragma unroll
    for (int t=0;t<4;t++){
        int s = (tid>>3) + t*32;
        int p0 = (tid&7)*8;
        bf16x8 xv = *(const bf16x8*)&xc[(tok0+s)*CONVD + h*64 + p0];
        float wv = dtv[base_h + s];
        #pragma unroll
        for (int e=0;e<8;e++) B1[(p0+e)*LP + s] = (bf16)((float)xv[e]*wv);
    }
    __syncthreads();
    f32x4v acc[2][4];
    #pragma unroll
    for (int mi=0;mi<2;mi++)
        #pragma unroll
        for (int ni=0;ni<4;ni++) acc[mi][ni] = {0.f,0.f,0.f,0.f};
    #pragma unroll
    for (int kk=0; kk<128; kk+=32){
        bf16x8 afr[2], bfr2[4];
        #pragma unroll
        for (int mi=0;mi<2;mi++)
            afr[mi] = *(const bf16x8*)&A1[(w*32 + mi*16 + (lane&15))*LP + kk + (lane>>4)*8];
        #pragma unroll
        for (int ni=0;ni<4;ni++)
            bfr2[ni] = *(const bf16x8*)&B1[(ni*16 + (lane&15))*LP + kk + (lane>>4)*8];
        #pragma unroll
        for (int mi=0;mi<2;mi++)
            #pragma unroll
            for (int ni=0;ni<4;ni++)
                acc[mi][ni] = __builtin_amdgcn_mfma_f32_16x16x32_bf16(afr[mi], bfr2[ni], acc[mi][ni], 0,0,0);
    }
    __syncthreads();
    {
        int l = tid>>1, n0 = (tid&1)*64;
        float e1 = expf(csl[l]);
        const bf16* crow = xc + (tok0+l)*CONVD + 4224;
        #pragma unroll
        for (int v=0;v<8;v++){
            bf16x8 cv = *(const bf16x8*)&crow[n0 + v*8];
            bf16x8 o;
            #pragma unroll
            for (int e=0;e<8;e++) o[e] = (bf16)((float)cv[e]*e1);
            *(bf16x8*)&A1[l*LP + n0 + v*8] = o;
        }
    }
    {
        int p = tid>>2, n0 = (tid&3)*32;
        const bf16* hrow = hst + (long)blk*8192 + (long)p*128 + n0;
        #pragma unroll
        for (int v=0;v<4;v++)
            *(bf16x8*)&B1[p*LP + n0 + v*8] = *(const bf16x8*)&hrow[v*8];
    }
    __syncthreads();
    #pragma unroll
    for (int kk=0; kk<128; kk+=32){
        bf16x8 afr[2], bfr2[4];
        #pragma unroll
        for (int mi=0;mi<2;mi++)
            afr[mi] = *(const bf16x8*)&A1[(w*32 + mi*16 + (lane&15))*LP + kk + (lane>>4)*8];
        #pragma unroll
        for (int ni=0;ni<4;ni++)
            bfr2[ni] = *(const bf16x8*)&B1[(ni*16 + (lane&15))*LP + kk + (lane>>4)*8];
        #pragma unroll
        for (int mi=0;mi<2;mi++)
            #pragma unroll
            for (int ni=0;ni<4;ni++)
                acc[mi][ni] = __builtin_amdgcn_mfma_f32_16x16x32_bf16(afr[mi], bfr2[ni], acc[mi][ni], 0,0,0);
    }
    #pragma unroll
    for (int mi=0;mi<2;mi++)
        #pragma unroll
        for (int ni=0;ni<4;ni++){
            int l0 = w*32 + mi*16 + (lane>>4)*4;
            int p  = ni*16 + (lane&15);
            #pragma unroll
            for (int j=0;j<4;j++)
                Ybf[(tok0 + l0 + j)*DI + h*64 + p] = (bf16)acc[mi][ni][j];
        }
}

// ---------------- gate (silu(z)) + D*x + RMSNorm + cast bf16 ----------------
__global__ __launch_bounds__(256) void gatenorm_kernel(const bf16* __restrict__ Ybf,
                                                       const bf16* __restrict__ zx,
                                                       const bf16* __restrict__ xc,
                                                       const float* __restrict__ Dp,
                                                       const float* __restrict__ nw,
                                                       bf16* __restrict__ ybn){
    __shared__ float red[4];
    int tok = blockIdx.x, tid = threadIdx.x;
    const bf16* yrow = Ybf + (long)tok*DI;
    const bf16* zrow = zx  + (long)tok*ZLD;
    const bf16* xrow = xc  + (long)tok*CONVD;
    float yg[16];
    float ss = 0.f;
    #pragma unroll
    for (int k=0;k<2;k++){
        int d = (tid + k*256)*8;
        bf16x8 yv = *(const bf16x8*)&yrow[d];
        bf16x8 zv = *(const bf16x8*)&zrow[d];
        bf16x8 xv = *(const bf16x8*)&xrow[d];
        float dh = Dp[d>>6];
        #pragma unroll
        for (int e=0;e<8;e++){
            float yy = (float)yv[e] + dh*(float)xv[e];
            float g = yy*silu_f((float)zv[e]);
            yg[k*8+e] = g;
            ss += g*g;
        }
    }
    #pragma unroll
    for (int off=32; off>0; off>>=1) ss += __shfl_down(ss, off, 64);
    if ((tid & 63) == 0) red[tid>>6] = ss;
    __syncthreads();
    float tot = red[0]+red[1]+red[2]+red[3];
    float scale = rsqrtf(tot/(float)DI + 1e-5f);
    #pragma unroll
    for (int k=0;k<2;k++){
        int d = (tid + k*256)*8;
        float4 w0 = *(const float4*)&nw[d];
        float4 w1 = *(const float4*)&nw[d+4];
        float wv[8] = {w0.x,w0.y,w0.z,w0.w,w1.x,w1.y,w1.z,w1.w};
        bf16x8 o;
        #pragma unroll
        for (int e=0;e<8;e++) o[e] = (bf16)(yg[k*8+e]*scale*wv[e]);
        *(bf16x8*)&ybn[(long)tok*DI + d] = o;
    }
}

// ---------------- launch ----------------
extern "C" void kernel_launch(void* const* d_in, const int* in_sizes, int n_in,
                              void* d_out, int out_size, void* d_ws, size_t ws_size,
                              hipStream_t stream){
    const float* hs      = (const float*)d_in[0];
    const float* W_in    = (const float*)d_in[1];
    const float* W_conv  = (const float*)d_in[2];
    const float* b_conv  = (const float*)d_in[3];
    const float* A_log   = (const float*)d_in[4];
    const float* Dp      = (const float*)d_in[5];
    const float* dt_bias = (const float*)d_in[6];
    const float* nw      = (const float*)d_in[7];
    const float* W_out   = (const float*)d_in[8];
    float* out = (float*)d_out;

    char* ws = (char*)d_ws;
    const size_t OFF_ZX    = 0;                    // bf16 [4096][8704]      71,303,168
    const size_t OFF_DTF   = 71303168;             // f32  [4096][64]         1,048,576
    const size_t OFF_XC    = 72351744;             // bf16 [4096][4352]      35,651,584
    const size_t OFF_DTV   = 108003328;            // f32                     1,048,576
    const size_t OFF_DACS  = 109051904;            //                         1,048,576
    const size_t OFF_CDEC  = 110100480;            // f32 [2048]                  8,192
    const size_t OFF_CB    = 110108672;            // f32 [32][128][128]      2,097,152
    const size_t OFF_SLOTA = 112205824;            // 67,108,864: hsb+winb -> states(bf16) -> Ybf
    const size_t OFF_SLOTB = 179314688;            // 33,554,432: tailpart -> BT -> hst(bf16) -> ybn
    const size_t OFF_WOUTB = 212869120;            // bf16 [2048][4096]      16,777,216

    bf16*  zx    = (bf16*)(ws + OFF_ZX);
    float* dtf   = (float*)(ws + OFF_DTF);
    bf16*  xc    = (bf16*)(ws + OFF_XC);
    float* dtv   = (float*)(ws + OFF_DTV);
    float* dacs  = (float*)(ws + OFF_DACS);
    float* cdec  = (float*)(ws + OFF_CDEC);
    float* cbuf  = (float*)(ws + OFF_CB);
    bf16*  hsb   = (bf16*)(ws + OFF_SLOTA);
    bf16*  winb  = (bf16*)(ws + OFF_SLOTA + 16777216);
    bf16*  states= (bf16*)(ws + OFF_SLOTA);
    bf16*  Ybf   = (bf16*)(ws + OFF_SLOTA);
    float* tpart = (float*)(ws + OFF_SLOTB);       // 4 x [4096][512] f32 GEMM1-tail partials
    bf16*  BTb   = (bf16*)(ws + OFF_SLOTB);        // bf16 [32][128][128] (1MB), after tailreduce
    bf16*  hst   = (bf16*)(ws + OFF_SLOTB);        // written by scan (after states consumed BT)
    bf16*  ybn   = (bf16*)(ws + OFF_SLOTB);
    bf16*  woutb = (bf16*)(ws + OFF_WOUTB);

    cvt_all_kernel<<<33792, 256, 0, stream>>>(hs, W_in, W_out, hsb, winb, woutb);

    // GEMM1: 256 tail blocks (256x128, split-K=4) + 512 bulk blocks (256x256)
    gemm1_kernel<<<768, 512, 0, stream>>>(hsb, winb, zx, tpart, 32, 16, DMODEL);
    tailreduce_kernel<<<2048, 256, 0, stream>>>(tpart, zx, dtf);

    mid1_kernel<<<3072, 256, 0, stream>>>(zx, W_conv, b_conv, dtf, A_log, dt_bias,
                                          xc, dtv, dacs, cdec);
    cb_mfma_kernel<<<32, 256, 0, stream>>>(xc, cbuf, BTb);
    states_mfma_kernel<<<2048, 256, 0, stream>>>(xc, BTb, dtv, dacs, states);
    scan_kernel<<<4096, 256, 0, stream>>>(states, cdec, hst);
    yfused_kernel<<<2048, 256, 0, stream>>>(xc, cbuf, hst, dtv, dacs, Ybf);
    gatenorm_kernel<<<4096, 256, 0, stream>>>(Ybf, zx, xc, Dp, nw, ybn);

    // GEMM2: [4096,4096] x [2048,4096]^T -> out f32 direct (256x128 tiles, 1 round)
    gemm256x128_kernel<<<256, 512, 0, stream>>>(ybn, woutb, out, 16, 16, DI, DMODEL);
}